// Round 7
// baseline (50.917 us; speedup 1.0000x reference)
//
#include <hip/hip_runtime.h>
#include <math.h>

#define BB 256
#define NN 196
#define DD 768
#define TDK 32
#define NHALF 2
#define DHALF (DD / NHALF)        // 384
#define NTILES (DHALF / TDK)      // 12
#define SROW 224                  // tile row stride in floats: 896 B = 0 mod 32 banks
#define NW 8                      // waves per block (512 threads)
#define NITEMS (NN * 8)           // 1568 load-side items; also 32*49 store items

typedef float f32x4 __attribute__((ext_vector_type(4)));

// grid (BB, 2): block (b, h) computes pos/conf for batch b (redundantly per
// half) then rearranges d-range [h*384, (h+1)*384).
// LDS tile uses XOR block-swizzle: element (d,p) lives at
//   d*SROW + ((p>>2) ^ ((d>>2)&7))*4 + (p&3)
// -> transpose-writes are 2-way (free), b128 reads ~conflict-free.
__global__ __launch_bounds__(512) void fused_kernel(
    const float* __restrict__ features,  // [B,N,D]
    const float* __restrict__ logits,    // [B,N,N]
    float* __restrict__ img,             // [B,D,N]
    float* __restrict__ conf_out)        // [B,N]
{
    const int b = blockIdx.x;
    const int h = blockIdx.y;
    const int t = threadIdx.x;

    __shared__ float sm[NW][NN];
    __shared__ float ss[NW][NN];
    __shared__ int   si[NW][NN];
    __shared__ int   winner_s[NN];
    __shared__ float tile[TDK * SROW];

    // ---------------- Phase A: pos + conf ----------------
    const int wv = t >> 6;               // wave 0..7 -> row chunk
    const int l  = t & 63;

    if (t < NN) winner_s[t] = -1;

    {
        const int i0 = (49 * wv) >> 1;           // (196*wv)/8
        const int i1 = (49 * (wv + 1)) >> 1;
        if (l < 49) {
            const float* basep = logits + (size_t)b * NN * NN + 4 * l;
            f32x4 m = {-INFINITY, -INFINITY, -INFINITY, -INFINITY};
            f32x4 s = {0.f, 0.f, 0.f, 0.f};
            int4 idx = make_int4(0, 0, 0, 0);
            #pragma unroll 4
            for (int i = i0; i < i1; ++i) {
                const f32x4 x = *reinterpret_cast<const f32x4*>(basep + (size_t)i * NN);
                f32x4 mn;
                mn.x = fmaxf(m.x, x.x); mn.y = fmaxf(m.y, x.y);
                mn.z = fmaxf(m.z, x.z); mn.w = fmaxf(m.w, x.w);
                idx.x = (x.x > m.x) ? i : idx.x;   // strict >: first occurrence
                idx.y = (x.y > m.y) ? i : idx.y;
                idx.z = (x.z > m.z) ? i : idx.z;
                idx.w = (x.w > m.w) ? i : idx.w;
                s.x = s.x * __expf(m.x - mn.x) + __expf(x.x - mn.x);
                s.y = s.y * __expf(m.y - mn.y) + __expf(x.y - mn.y);
                s.z = s.z * __expf(m.z - mn.z) + __expf(x.z - mn.z);
                s.w = s.w * __expf(m.w - mn.w) + __expf(x.w - mn.w);
                m = mn;
            }
            const int c = 4 * l;
            sm[wv][c + 0] = m.x; ss[wv][c + 0] = s.x; si[wv][c + 0] = idx.x;
            sm[wv][c + 1] = m.y; ss[wv][c + 1] = s.y; si[wv][c + 1] = idx.y;
            sm[wv][c + 2] = m.z; ss[wv][c + 2] = s.z; si[wv][c + 2] = idx.z;
            sm[wv][c + 3] = m.w; ss[wv][c + 3] = s.w; si[wv][c + 3] = idx.w;
        }
    }
    __syncthreads();

    if (t < NN) {
        const int j = t;
        float m = -INFINITY;
        int idx = 0;
        #pragma unroll
        for (int ww = 0; ww < NW; ++ww) {    // ascending rows: earliest chunk wins ties
            const float mg = sm[ww][j];
            if (mg > m) { m = mg; idx = si[ww][j]; }
        }
        float s = 0.0f;
        #pragma unroll
        for (int ww = 0; ww < NW; ++ww)
            s += ss[ww][j] * __expf(sm[ww][j] - m);
        if (h == 0) conf_out[b * NN + j] = 1.0f / s;
        atomicMax(&winner_s[idx], j);        // winner[p] = max j with pos[j]==p
    }
    __syncthreads();                         // winner_s ready; sm/ss/si dead

    // ---------------- Phase B: gather + smooth + transpose-store ----------------
    const float* fb = features + (size_t)b * NN * DD;
    const int D0 = h * DHALF;
    float* ob = img + (size_t)b * DD * NN + (size_t)D0 * NN;

    // Load-side items: item = r*8 + k; r = row 0..195, k*4 = d offset in tile.
    // 1568 items / 512 threads -> 4 slots per thread (ceil).
    int  rr[4], k4[4], wn[4];
    bool act[4];
    #pragma unroll
    for (int i = 0; i < 4; ++i) {
        const int item = t + 512 * i;
        act[i] = (item < NITEMS);
        rr[i]  = act[i] ? (item >> 3) : 0;
        k4[i]  = (item & 7) * 4;
        wn[i]  = act[i] ? winner_s[rr[i]] : -1;
    }

    const f32x4 zero = {0.f, 0.f, 0.f, 0.f};
    f32x4 cur[4], nxt[4];
    #pragma unroll
    for (int i = 0; i < 4; ++i)
        cur[i] = (wn[i] >= 0)
            ? *reinterpret_cast<const f32x4*>(fb + (size_t)wn[i] * DD + D0 + k4[i])
            : zero;

    for (int kt = 0; kt < NTILES; ++kt) {
        // Swizzled transpose-write (2-way bank pattern: free).
        #pragma unroll
        for (int i = 0; i < 4; ++i) {
            if (act[i]) {
                const int r  = rr[i];
                const int kb = k4[i] >> 2;                       // (d_local>>2)&7
                const int col = (((r >> 2) ^ kb) << 2) + (r & 3);
                tile[(k4[i] + 0) * SROW + col] = cur[i].x;
                tile[(k4[i] + 1) * SROW + col] = cur[i].y;
                tile[(k4[i] + 2) * SROW + col] = cur[i].z;
                tile[(k4[i] + 3) * SROW + col] = cur[i].w;
            }
        }
        // Prefetch next tile; latency hides under this tile's store phase.
        #pragma unroll
        for (int i = 0; i < 4; ++i) nxt[i] = zero;
        if (kt + 1 < NTILES) {
            const int dn = D0 + (kt + 1) * TDK;
            #pragma unroll
            for (int i = 0; i < 4; ++i)
                if (wn[i] >= 0)
                    nxt[i] = *reinterpret_cast<const f32x4*>(fb + (size_t)wn[i] * DD + dn + k4[i]);
        }
        __syncthreads();                     // tile fully written

        // Store phase: q -> (dl = q/49, c = q%49); global addr = base + 16q bytes.
        const int dg0 = kt * TDK;
        #pragma unroll
        for (int it = 0; it < 4; ++it) {
            const int q = t + 512 * it;
            if (q < TDK * 49) {
                const int dl  = q / 49;
                const int c   = q - 49 * dl;
                const int key = (dl >> 2) & 7;
                const float* row = &tile[dl * SROW];
                const f32x4 ctr = *reinterpret_cast<const f32x4*>(row + ((c ^ key) << 2));
                const float left  = (c > 0)  ? row[(((c - 1) ^ key) << 2) + 3] : 0.0f;
                const float right = (c < 48) ? row[ ((c + 1) ^ key) << 2      ] : 0.0f;
                const int p0 = 4 * c;
                f32x4 o;
                o.x = (p0 == 0)          ? ctr.x : (left  + ctr.x + ctr.y) * (1.0f / 3.0f);
                o.y = (ctr.x + ctr.y + ctr.z) * (1.0f / 3.0f);
                o.z = (ctr.y + ctr.z + ctr.w) * (1.0f / 3.0f);
                o.w = (p0 + 3 == NN - 1) ? ctr.w : (ctr.z + ctr.w + right) * (1.0f / 3.0f);
                float* dst = ob + (size_t)(dg0 + dl) * NN + p0;
                __builtin_nontemporal_store(o, reinterpret_cast<f32x4*>(dst));
            }
        }
        #pragma unroll
        for (int i = 0; i < 4; ++i) cur[i] = nxt[i];
        __syncthreads();                     // store phase done before next LDS write
    }
}

extern "C" void kernel_launch(void* const* d_in, const int* in_sizes, int n_in,
                              void* d_out, int out_size, void* d_ws, size_t ws_size,
                              hipStream_t stream) {
    const float* features = (const float*)d_in[0];
    const float* logits   = (const float*)d_in[1];

    float* out  = (float*)d_out;
    float* img  = out;                              // B*D*N floats
    float* conf = out + (size_t)BB * DD * NN;       // B*N floats

    dim3 grid(BB, NHALF);
    fused_kernel<<<grid, 512, 0, stream>>>(features, logits, img, conf);
}